// Round 8
// baseline (312.213 us; speedup 1.0000x reference)
//
#include <hip/hip_runtime.h>
#include <math.h>
#include <limits.h>

#define BB 8
#define SS 4096
#define HH 1024
#define EE 256
#define KK 64
#define HQ 256
#define NEGF -1e30f

typedef short bf16x8 __attribute__((ext_vector_type(8)));
typedef float f32x4  __attribute__((ext_vector_type(4)));

__device__ inline short f2bf(float x) {
    unsigned u = __float_as_uint(x);
    unsigned r = (u + 0x7fffu + ((u >> 16) & 1u)) >> 16;   // RNE
    return (short)r;
}

// pack two f32 into two bf16 (round-half-up)
__device__ inline unsigned pk2bf(float lo, float hi) {
    unsigned a = __float_as_uint(lo) + 0x8000u;
    unsigned b = __float_as_uint(hi) + 0x8000u;
    return (a >> 16) | (b & 0xffff0000u);
}

// Both weight conversions in one kernel. dst[kb][n][kk] = bf16(src[(kb*32+kk)*HQ+n])
__global__ __launch_bounds__(256) void convert_both_kernel(
    const float* __restrict__ tok_w1, const float* __restrict__ blk_w1,
    short* __restrict__ w1s_tok, short* __restrict__ w1s_blk)
{
    const int kb = blockIdx.x & 31, which = blockIdx.x >> 5;
    const float* src = which ? blk_w1 : tok_w1;
    short* dst = which ? w1s_blk : w1s_tok;
    const int n = threadIdx.x;
    for (int kk = 0; kk < 32; kk++)
        dst[kb * 8192 + n * 32 + kk] = f2bf(src[(kb * 32 + kk) * HQ + n]);
}

// Row scores: 32 rows/WG x 256 cols. The WHOLE 32x1024 X tile is staged to LDS
// once with row-contiguous 1KB wave reads (f32->bf16 in flight), then the
// K-loop runs barrier-free: A from LDS (ds_read_b128, even bank spread),
// B register-double-buffered streaming from L2. Latency off the critical path.
#define APAD 1032   // 1024 + 8 bf16 pad (keeps 16B alignment, breaks bank stride)
__global__ __launch_bounds__(256) void mfma_score5_kernel(
    const float* __restrict__ X, const short* __restrict__ w1s,
    const float* __restrict__ b1, const float* __restrict__ w2,
    const float* __restrict__ b2, float* __restrict__ out)
{
    __shared__ __attribute__((aligned(16))) short As[32 * APAD];  // 66 KB
    __shared__ float part[4][32];

    const int t = threadIdx.x;
    const int wv = t >> 6, lane = t & 63, lo = lane & 15, q = lane >> 4;
    const long row0 = (long)blockIdx.x * 32;

    // ---- stage whole tile: round i = row i; wave w covers floats [256w,256w+256)
    const float* xbase = X + row0 * HH + wv * 256 + lane * 4;
#pragma unroll 8
    for (int i = 0; i < 32; i++) {
        float4 v = *(const float4*)(xbase + (long)i * HH);
        unsigned u0 = pk2bf(v.x, v.y), u1 = pk2bf(v.z, v.w);
        uint2* d = (uint2*)(&As[i * APAD + wv * 256 + lane * 4]);
        *d = (uint2){u0, u1};
    }
    __syncthreads();   // the only barrier before the epilogue

    f32x4 acc[2][4];
#pragma unroll
    for (int i = 0; i < 2; i++)
#pragma unroll
        for (int j = 0; j < 4; j++) acc[i][j] = (f32x4){0.f, 0.f, 0.f, 0.f};

    // B: wave wv, frag ct: lane(q,lo) -> n = wv*64+ct*16+lo, k = kb*32+q*8
    const short* wp = w1s + (wv * 64 + lo) * 32 + q * 8;
    // A-frag base: row lo (+rt*16), k-offset q*8 shorts (+kb*32).
    // r6 BUG was q*16 here -> OOB LDS reads -> NaN. Must be q*8.
    const int aofs = lo * APAD + q * 8;

    bf16x8 bA[4], bB[4];
#pragma unroll
    for (int ct = 0; ct < 4; ct++)
        bA[ct] = *(const bf16x8*)(wp + ct * 512);

    for (int kb = 0; kb < 32; kb += 2) {
        {   // prefetch kb+1 B; compute kb with bA
#pragma unroll
            for (int ct = 0; ct < 4; ct++)
                bB[ct] = *(const bf16x8*)(wp + (kb + 1) * 8192 + ct * 512);
            bf16x8 af[2];
#pragma unroll
            for (int rt = 0; rt < 2; rt++)
                af[rt] = *(bf16x8*)(&As[aofs + rt * 16 * APAD + kb * 32]);
#pragma unroll
            for (int rt = 0; rt < 2; rt++)
#pragma unroll
                for (int ct = 0; ct < 4; ct++)
                    acc[rt][ct] = __builtin_amdgcn_mfma_f32_16x16x32_bf16(
                        af[rt], bA[ct], acc[rt][ct], 0, 0, 0);
        }
        {   // prefetch kb+2 B; compute kb+1 with bB
            const int k2 = (kb + 2 < 32) ? kb + 2 : 31;
#pragma unroll
            for (int ct = 0; ct < 4; ct++)
                bA[ct] = *(const bf16x8*)(wp + k2 * 8192 + ct * 512);
            bf16x8 af[2];
#pragma unroll
            for (int rt = 0; rt < 2; rt++)
                af[rt] = *(bf16x8*)(&As[aofs + rt * 16 * APAD + (kb + 1) * 32]);
#pragma unroll
            for (int rt = 0; rt < 2; rt++)
#pragma unroll
                for (int ct = 0; ct < 4; ct++)
                    acc[rt][ct] = __builtin_amdgcn_mfma_f32_16x16x32_bf16(
                        af[rt], bB[ct], acc[rt][ct], 0, 0, 0);
        }
    }

    // epilogue: rowpart[rt][r] = sum_c tanh(acc + b1[c]) * w2[c]
    float rowpart[2][4];
#pragma unroll
    for (int rt = 0; rt < 2; rt++)
#pragma unroll
        for (int r = 0; r < 4; r++) rowpart[rt][r] = 0.f;
#pragma unroll
    for (int ct = 0; ct < 4; ct++) {
        const int cc = wv * 64 + ct * 16 + lo;
        const float b1c = b1[cc], w2c = w2[cc];
#pragma unroll
        for (int rt = 0; rt < 2; rt++)
#pragma unroll
            for (int r = 0; r < 4; r++)
                rowpart[rt][r] += tanhf(acc[rt][ct][r] + b1c) * w2c;
    }
#pragma unroll
    for (int rt = 0; rt < 2; rt++)
#pragma unroll
        for (int r = 0; r < 4; r++) {
            float v = rowpart[rt][r];
            v += __shfl_down(v, 8, 64);
            v += __shfl_down(v, 4, 64);
            v += __shfl_down(v, 2, 64);
            v += __shfl_down(v, 1, 64);
            rowpart[rt][r] = v;   // valid where lo==0
        }
    if (lo == 0)
#pragma unroll
        for (int rt = 0; rt < 2; rt++)
#pragma unroll
            for (int r = 0; r < 4; r++)
                part[wv][rt * 16 + q * 4 + r] = rowpart[rt][r];
    __syncthreads();
    if (t < 32)
        out[row0 + t] = part[0][t] + part[1][t] + part[2][t] + part[3][t] + b2[0];
}

// Per (b,k): masked max + denom; write normalized wtok; zero embed row;
// k==0 also zeroes wtok[0, start).
__global__ __launch_bounds__(256) void block_stats_kernel(
    const float* __restrict__ scores, const int* __restrict__ mask,
    const int* __restrict__ bnd, float* __restrict__ bden,
    float* __restrict__ wtok, float* __restrict__ embed)
{
    const int b = blockIdx.x >> 6, k = blockIdx.x & 63;
    const int start = bnd[b * KK + k];
    const int end = (k == KK - 1) ? SS : bnd[b * KK + k + 1];
    const int tid = threadIdx.x;
    __shared__ float r[4];
    __shared__ float mshared, dshared;

    *((float4*)(embed + (long)blockIdx.x * HH) + tid) = (float4){0.f, 0.f, 0.f, 0.f};
    if (k == 0)
        for (int s = tid; s < start; s += 256) wtok[b * SS + s] = 0.f;

    float m = NEGF;
    for (int s = start + tid; s < end; s += 256)
        if (mask[b * SS + s] == 1) m = fmaxf(m, scores[b * SS + s]);
    for (int off = 32; off > 0; off >>= 1) m = fmaxf(m, __shfl_down(m, off, 64));
    if ((tid & 63) == 0) r[tid >> 6] = m;
    __syncthreads();
    if (tid == 0) mshared = fmaxf(fmaxf(r[0], r[1]), fmaxf(r[2], r[3]));
    __syncthreads();
    m = mshared;

    float d = 0.f;
    for (int s = start + tid; s < end; s += 256)
        if (mask[b * SS + s] == 1) d += expf(scores[b * SS + s] - m);
    for (int off = 32; off > 0; off >>= 1) d += __shfl_down(d, off, 64);
    __syncthreads();
    if ((tid & 63) == 0) r[tid >> 6] = d;
    __syncthreads();
    if (tid == 0) {
        float den = r[0] + r[1] + r[2] + r[3];
        bden[blockIdx.x] = den;
        dshared = (den > 0.f) ? 1.f / fmaxf(den, 1e-30f) : 0.f;
    }
    __syncthreads();
    const float inv = dshared;
    for (int s = start + tid; s < end; s += 256)
        wtok[b * SS + s] = (mask[b * SS + s] == 1) ? expf(scores[b * SS + s] - m) * inv : 0.f;
}

// Weighted accumulation: grid = B x (S/16); thread t owns h = t,+256,+512,+768.
// wtok chunk in LDS; fast path for boundary-free chunks.
#define TCH 16
__global__ __launch_bounds__(256) void block_embed4_kernel(
    const float* __restrict__ hidden, const float* __restrict__ wtok,
    const int* __restrict__ bnd, float* __restrict__ embed)
{
    const int b = blockIdx.x >> 8;
    const int ch = blockIdx.x & 255;
    const int t = threadIdx.x;
    __shared__ int bsh[KK];
    __shared__ float wsh[TCH];
    const int s0 = ch * TCH, s1 = s0 + TCH;
    if (t < KK) bsh[t] = bnd[b * KK + t];
    if (t >= 64 && t < 64 + TCH) wsh[t - 64] = wtok[b * SS + s0 + (t - 64)];
    __syncthreads();

    int cur = -1;
#pragma unroll
    for (int i = 0; i < KK; i++) cur = (bsh[i] <= s0) ? i : cur;
    const int nxt = (cur + 1 < KK) ? bsh[cur + 1] : INT_MAX;

    const float* hr0 = hidden + ((long)b * SS + s0) * HH + t;
    float a0 = 0.f, a1 = 0.f, a2 = 0.f, a3 = 0.f;

    if (nxt >= s1 && cur >= 0) {
#pragma unroll
        for (int i = 0; i < TCH; i++) {
            const float w = wsh[i];
            const float* hr = hr0 + (long)i * HH;
            a0 = fmaf(w, hr[0], a0);
            a1 = fmaf(w, hr[256], a1);
            a2 = fmaf(w, hr[512], a2);
            a3 = fmaf(w, hr[768], a3);
        }
        float* e = embed + ((long)b * KK + cur) * HH;
        atomicAdd(e + t, a0); atomicAdd(e + t + 256, a1);
        atomicAdd(e + t + 512, a2); atomicAdd(e + t + 768, a3);
        return;
    }

    bool any = false;
    for (int s = s0; s < s1; s++) {
        while (cur + 1 < KK && bsh[cur + 1] <= s) {
            if (any) {
                float* e = embed + ((long)b * KK + cur) * HH;
                atomicAdd(e + t, a0); atomicAdd(e + t + 256, a1);
                atomicAdd(e + t + 512, a2); atomicAdd(e + t + 768, a3);
                a0 = a1 = a2 = a3 = 0.f; any = false;
            }
            cur++;
        }
        if (cur < 0) continue;
        const float w = wsh[s - s0];
        const float* hr = hr0 + (long)(s - s0) * HH;
        a0 = fmaf(w, hr[0], a0);
        a1 = fmaf(w, hr[256], a1);
        a2 = fmaf(w, hr[512], a2);
        a3 = fmaf(w, hr[768], a3);
        any = true;
    }
    if (any) {
        float* e = embed + ((long)b * KK + cur) * HH;
        atomicAdd(e + t, a0); atomicAdd(e + t + 256, a1);
        atomicAdd(e + t + 512, a2); atomicAdd(e + t + 768, a3);
    }
}

// Fused finalize A+B (grid B*8): block softmax -> func slice (128 h) in LDS ->
// partial GEMV -> osum[(b*8+hc)*EE + e] (non-atomic partials).
__global__ __launch_bounds__(256) void finalize_ab_kernel(
    const float* __restrict__ embed, const float* __restrict__ bscores,
    const float* __restrict__ bden, const float* __restrict__ out_w,
    float* __restrict__ osum)
{
    const int b = blockIdx.x >> 3, hc = blockIdx.x & 7;
    const int t = threadIdx.x;
    __shared__ float bw[KK];
    __shared__ float fpart[2][128];
    __shared__ float fsh[128];

    if (t < KK) {
        float s = (bden[b * KK + t] > 0.f) ? bscores[b * KK + t] : NEGF;
        float m = s;
        for (int off = 32; off > 0; off >>= 1) m = fmaxf(m, __shfl_xor(m, off, 64));
        float e = expf(s - m);
        float d = e;
        for (int off = 32; off > 0; off >>= 1) d += __shfl_xor(d, off, 64);
        bw[t] = e / d;
    }
    __syncthreads();

    {
        const int hh = t & 127, kh = t >> 7;
        const float* ep = embed + ((long)b * KK + kh * 32) * HH + hc * 128 + hh;
        float f = 0.f;
#pragma unroll 8
        for (int k2 = 0; k2 < 32; k2++)
            f = fmaf(bw[kh * 32 + k2], ep[(long)k2 * HH], f);
        fpart[kh][hh] = f;
    }
    __syncthreads();
    if (t < 128) fsh[t] = fpart[0][t] + fpart[1][t];
    __syncthreads();

    float acc = 0.f;
    const float* wpp = out_w + (long)(hc * 128) * EE + t;
#pragma unroll 8
    for (int h = 0; h < 128; h++)
        acc = fmaf(fsh[h], wpp[(long)h * EE], acc);
    osum[(long)(b * 8 + hc) * EE + t] = acc;
}

// finalize C (grid B): reduce 8 partials + bias + L2 normalize
__global__ __launch_bounds__(256) void finalize_c_kernel(
    const float* __restrict__ osum, const float* __restrict__ out_b,
    float* __restrict__ outp)
{
    const int b = blockIdx.x, t = threadIdx.x;
    __shared__ float r4[4];
    float o = out_b[t];
#pragma unroll
    for (int hc = 0; hc < 8; hc++)
        o += osum[(long)(b * 8 + hc) * EE + t];
    float sq = o * o;
    for (int off = 32; off > 0; off >>= 1) sq += __shfl_down(sq, off, 64);
    if ((t & 63) == 0) r4[t >> 6] = sq;
    __syncthreads();
    const float nrm = sqrtf(r4[0] + r4[1] + r4[2] + r4[3]);
    outp[b * EE + t] = o / fmaxf(nrm, 1e-12f);
}

extern "C" void kernel_launch(void* const* d_in, const int* in_sizes, int n_in,
                              void* d_out, int out_size, void* d_ws, size_t ws_size,
                              hipStream_t stream) {
    const float* hidden  = (const float*)d_in[0];
    const int*   mask    = (const int*)  d_in[1];
    const int*   bnd     = (const int*)  d_in[2];
    const float* tok_w1  = (const float*)d_in[3];
    const float* tok_b1  = (const float*)d_in[4];
    const float* tok_w2  = (const float*)d_in[5];
    const float* tok_b2  = (const float*)d_in[6];
    const float* blk_w1  = (const float*)d_in[7];
    const float* blk_b1  = (const float*)d_in[8];
    const float* blk_w2  = (const float*)d_in[9];
    const float* blk_b2  = (const float*)d_in[10];
    const float* out_w   = (const float*)d_in[11];
    const float* out_b   = (const float*)d_in[12];

    float* ws      = (float*)d_ws;
    float* wtok    = ws;                       // [32768]
    float* embed   = ws + 32768;               // [524288]
    float* scores  = ws + 557056;              // [32768]
    float* bden    = ws + 589824;              // [512]
    float* bscores = ws + 590336;              // [512]
    float* osum    = ws + 590848;              // [16384]
    short* w1s_tok = (short*)(ws + 607232);    // [262144] bf16
    short* w1s_blk = w1s_tok + 262144;         // [262144] bf16

    convert_both_kernel<<<64, 256, 0, stream>>>(tok_w1, blk_w1, w1s_tok, w1s_blk);
    mfma_score5_kernel<<<BB * SS / 32, 256, 0, stream>>>(
        hidden, w1s_tok, tok_b1, tok_w2, tok_b2, scores);
    block_stats_kernel<<<BB * KK, 256, 0, stream>>>(
        scores, mask, bnd, bden, wtok, embed);
    block_embed4_kernel<<<BB * SS / TCH, 256, 0, stream>>>(hidden, wtok, bnd, embed);
    mfma_score5_kernel<<<BB * KK / 32, 256, 0, stream>>>(
        embed, w1s_blk, blk_b1, blk_w2, blk_b2, bscores);
    finalize_ab_kernel<<<BB * 8, 256, 0, stream>>>(
        embed, bscores, bden, out_w, osum);
    finalize_c_kernel<<<BB, 256, 0, stream>>>(osum, out_b, (float*)d_out);
}